// Round 1
// baseline (198.075 us; speedup 1.0000x reference)
//
#include <hip/hip_runtime.h>
#include <math.h>

// Problem constants (from reference): B=32, A=3, S=52, C=80
constexpr int NCELL = 32 * 3 * 52 * 52;   // 259584
constexpr int PS = 85;                    // prediction channels (5 + C)
constexpr int TS = 6;                     // target channels (obj, 4 box, cls)
constexpr int NC = 80;                    // classes

// Accumulator layout in d_ws (6 floats):
// 0: sum bce over noobj
// 1: n_noobj
// 2: sum (p_obj - iou*tobj)^2 over obj
// 3: n_obj
// 4: sum box_se over obj
// 5: sum nll over obj

__global__ __launch_bounds__(256) void yolo_main(const float* __restrict__ pred,
                                                 const float* __restrict__ tgt,
                                                 float* __restrict__ acc)
{
    int cell = blockIdx.x * 256 + threadIdx.x;
    float s0 = 0.f, s1 = 0.f, s2 = 0.f, s3 = 0.f, s4 = 0.f, s5 = 0.f;

    if (cell < NCELL) {
        const float* p = pred + (long long)cell * PS;
        const float* t = tgt  + (long long)cell * TS;

        float t0 = t[0], t1 = t[1], t2 = t[2], t3 = t[3], t4 = t[4], t5 = t[5];
        float p0 = p[0], p1 = p[1], p2 = p[2], p3 = p[3], p4 = p[4];

        bool obj   = (t0 == 1.0f);
        bool noobj = (t0 == 0.0f);

        // --- BCE-with-logits on objectness channel ---
        float bce = fmaxf(p0, 0.0f) - p0 * t0 + log1pf(expf(-fabsf(p0)));

        // --- midpoint IoU: b1 = pred[0:4] (as in reference!), b2 = target[1:5] ---
        float b1x1 = p0 - p2 * 0.5f, b1y1 = p1 - p3 * 0.5f;
        float b1x2 = p0 + p2 * 0.5f, b1y2 = p1 + p3 * 0.5f;
        float b2x1 = t1 - t3 * 0.5f, b2y1 = t2 - t4 * 0.5f;
        float b2x2 = t1 + t3 * 0.5f, b2y2 = t2 + t4 * 0.5f;
        float xi1 = fmaxf(b1x1, b2x1), yi1 = fmaxf(b1y1, b2y1);
        float xi2 = fminf(b1x2, b2x2), yi2 = fminf(b1y2, b2y2);
        float inter = fmaxf(xi2 - xi1, 0.0f) * fmaxf(yi2 - yi1, 0.0f);
        float a1 = fabsf((b1x2 - b1x1) * (b1y2 - b1y1));
        float a2 = fabsf((b2x2 - b2x1) * (b2y2 - b2y1));
        float iou = inter / (a1 + a2 - inter + 1e-6f);

        // --- object loss term ---
        float pobj = 1.0f / (1.0f + expf(-p0));
        float dob = pobj - iou * t0;
        float objterm = dob * dob;

        // --- box loss term (sigmoid on pred[1:5]) ---
        float d1 = 1.0f / (1.0f + expf(-p1)) - t1;
        float d2 = 1.0f / (1.0f + expf(-p2)) - t2;
        float d3 = 1.0f / (1.0f + expf(-p3)) - t3;
        float d4 = 1.0f / (1.0f + expf(-p4)) - t4;
        float boxse = d1 * d1 + d2 * d2 + d3 * d3 + d4 * d4;

        // --- class NLL: log-softmax over 80 logits ---
        float m = -INFINITY;
        #pragma unroll 8
        for (int c = 0; c < NC; ++c) m = fmaxf(m, p[5 + c]);
        float se = 0.0f;
        #pragma unroll 8
        for (int c = 0; c < NC; ++c) se += expf(p[5 + c] - m);
        int lbl = (int)t5;
        float nll = logf(se) - (p[5 + lbl] - m);

        if (noobj) { s0 = bce; s1 = 1.0f; }
        if (obj)   { s2 = objterm; s3 = 1.0f; s4 = boxse; s5 = nll; }
    }

    // --- wave (64-lane) reduction ---
    #pragma unroll
    for (int off = 32; off > 0; off >>= 1) {
        s0 += __shfl_down(s0, off);
        s1 += __shfl_down(s1, off);
        s2 += __shfl_down(s2, off);
        s3 += __shfl_down(s3, off);
        s4 += __shfl_down(s4, off);
        s5 += __shfl_down(s5, off);
    }

    // --- cross-wave reduction in LDS (4 waves of 64 in a 256 block) ---
    __shared__ float red[4][6];
    int lane = threadIdx.x & 63;
    int wid  = threadIdx.x >> 6;
    if (lane == 0) {
        red[wid][0] = s0; red[wid][1] = s1; red[wid][2] = s2;
        red[wid][3] = s3; red[wid][4] = s4; red[wid][5] = s5;
    }
    __syncthreads();
    if (threadIdx.x == 0) {
        float a0 = 0.f, a1 = 0.f, a2 = 0.f, a3 = 0.f, a4 = 0.f, a5 = 0.f;
        #pragma unroll
        for (int w = 0; w < 4; ++w) {
            a0 += red[w][0]; a1 += red[w][1]; a2 += red[w][2];
            a3 += red[w][3]; a4 += red[w][4]; a5 += red[w][5];
        }
        atomicAdd(&acc[0], a0);
        atomicAdd(&acc[1], a1);
        atomicAdd(&acc[2], a2);
        atomicAdd(&acc[3], a3);
        atomicAdd(&acc[4], a4);
        atomicAdd(&acc[5], a5);
    }
}

__global__ void yolo_final(const float* __restrict__ acc, float* __restrict__ out)
{
    if (threadIdx.x == 0 && blockIdx.x == 0) {
        float n_noobj = acc[1];
        float n_obj   = acc[3];
        // return order: (LAMBDA_BOX*box, LAMBDA_OBJ*object, LAMBDA_NOOBJ*noobj, LAMBDA_CLASS*class)
        out[0] = 5.0f * acc[4] / fmaxf(n_obj * 4.0f, 1.0f);
        out[1] = 1.0f * acc[2] / fmaxf(n_obj, 1.0f);
        out[2] = 0.5f * acc[0] / fmaxf(n_noobj, 1.0f);
        out[3] = 1.0f * acc[5] / fmaxf(n_obj, 1.0f);
    }
}

extern "C" void kernel_launch(void* const* d_in, const int* in_sizes, int n_in,
                              void* d_out, int out_size, void* d_ws, size_t ws_size,
                              hipStream_t stream)
{
    const float* pred = (const float*)d_in[0];
    const float* tgt  = (const float*)d_in[1];
    float* out = (float*)d_out;
    float* acc = (float*)d_ws;

    hipMemsetAsync(acc, 0, 6 * sizeof(float), stream);

    int grid = (NCELL + 255) / 256;
    yolo_main<<<grid, 256, 0, stream>>>(pred, tgt, acc);
    yolo_final<<<1, 64, 0, stream>>>(acc, out);
}